// Round 13
// baseline (152.236 us; speedup 1.0000x reference)
//
#include <hip/hip_runtime.h>
#include <hip/hip_bf16.h>

// Problem constants (fixed by setup_inputs)
constexpr int Bc  = 8;
constexpr int Qn  = 900;
constexpr int Sn  = 21760;

__constant__ int LVL_W[4]     = {128, 64, 32, 16};
__constant__ int LVL_H[4]     = {128, 64, 32, 16};
__constant__ int LVL_START[4] = {0, 16384, 20480, 21504};

typedef __attribute__((ext_vector_type(8))) short short8;
typedef __attribute__((ext_vector_type(4))) float f32x4;

__device__ __forceinline__ unsigned short f2bf(float x) {
    union { float f; unsigned int u; } z; z.f = x;
    unsigned int r = (z.u + 0x7FFF + ((z.u >> 16) & 1)) >> 16;   // RTN-even
    return (unsigned short)r;
}
__device__ __forceinline__ float bf2f(unsigned short u) {
    union { unsigned int i; float f; } z;
    z.i = ((unsigned int)u) << 16;
    return z.f;
}

// ---------------------------------------------------------------------------
// Pre-pass: pack a [K=256][N] f32 row-major weight into bf16 MFMA fragment
// order. frag_id = ntile*8 + kstep; lane l supplies
// W[k = kstep*32 + (l>>4)*8 + j][n = ntile*16 + (l&15)], j=0..7.
__global__ __launch_bounds__(256) void wfrag_k(const float* __restrict__ W, int N,
                                               unsigned short* __restrict__ out) {
    int gid = blockIdx.x * 256 + threadIdx.x;
    int frag = gid >> 6, lane = gid & 63;
    int ntile = frag >> 3, s = frag & 7;
    int n = ntile * 16 + (lane & 15);
    int kb = s * 32 + (lane >> 4) * 8;
    unsigned short* o = out + (size_t)gid * 8;
#pragma unroll
    for (int j = 0; j < 8; ++j)
        o[j] = f2bf(W[(size_t)(kb + j) * N + n]);
}

// ---------------------------------------------------------------------------
// value = ehs @ W_value + b  via bf16 MFMA. M=174080 = 680 blocks x 4 tiles x 64.
// T3 minimum-2-phase pipeline: each block grid-strides 4 m-tiles with
// double-buffered LDS. Schedule per tile t:
//   { issue global loads for t+1  ||  k-loop on buf[t&1] }
//   -> C-store(t) -> cvt+ds_write t+1 into buf[(t+1)&1] -> barrier.
// Stage latency (HBM) hides under the k-loop instead of serializing with it
// (r6-r12: stage->barrier->compute lockstep pinned this kernel at ~104us
// with every pipe <25% busy).
__global__ __launch_bounds__(512) void gemm_value_mfma(const float* __restrict__ A,
                                                       const unsigned short* __restrict__ Wfrag,
                                                       const float* __restrict__ bias,
                                                       unsigned short* __restrict__ C) {
    __shared__ unsigned short As[2 * 16384];   // 2 x 32 KB, XOR-swizzled rows

    const int t    = threadIdx.x;
    const int blk  = blockIdx.x;              // 0..679
    const int lane = t & 63;
    const int w    = t >> 6;                  // 0..7
    const int wr   = w >> 2, wc = w & 3;      // wave grid 2x4
    const int lq   = lane >> 4, lr = lane & 15;

    // Per-thread stage chunk LDS indices (chunk c = i*512+t; row=c>>5)
    int sidx[4];
#pragma unroll
    for (int i = 0; i < 4; ++i) {
        int c = i * 512 + t;
        int row = c >> 5;
        int kus = (c & 31) * 8;
        sidx[i] = row * 256 + (kus ^ ((row & 7) << 3));
    }

    const float4* A4 = reinterpret_cast<const float4*>(A);
    float4 ld[4][2];

    auto stage_load = [&](int bm) {          // issue 8 global loads (stay in flight)
        const float4* src = A4 + (size_t)bm * 4096;
#pragma unroll
        for (int i = 0; i < 4; ++i) {
            int c = i * 512 + t;
            ld[i][0] = src[c * 2];
            ld[i][1] = src[c * 2 + 1];
        }
    };
    auto stage_write = [&](int bufsel) {     // cvt + ds_write (waits loads here)
        unsigned short* buf = &As[bufsel * 16384];
#pragma unroll
        for (int i = 0; i < 4; ++i) {
            union { short8 v; unsigned short u[8]; } pk;
            pk.u[0] = f2bf(ld[i][0].x); pk.u[1] = f2bf(ld[i][0].y);
            pk.u[2] = f2bf(ld[i][0].z); pk.u[3] = f2bf(ld[i][0].w);
            pk.u[4] = f2bf(ld[i][1].x); pk.u[5] = f2bf(ld[i][1].y);
            pk.u[6] = f2bf(ld[i][1].z); pk.u[7] = f2bf(ld[i][1].w);
            *reinterpret_cast<short8*>(&buf[sidx[i]]) = pk.v;
        }
    };

    // Hoisted bias (this wave's 4 ntiles)
    float4 bb[4];
#pragma unroll
    for (int nt = 0; nt < 4; ++nt)
        bb[nt] = *reinterpret_cast<const float4*>(&bias[wc * 64 + nt * 16 + lq * 4]);

    const int bm0 = blk * 4;
    stage_load(bm0);
    stage_write(0);
    __syncthreads();

#pragma unroll 1
    for (int tt = 0; tt < 4; ++tt) {
        if (tt < 3) stage_load(bm0 + tt + 1);       // in flight across k-loop

        const unsigned short* buf = &As[(tt & 1) * 16384];
        f32x4 acc[2][4];
#pragma unroll
        for (int mt = 0; mt < 2; ++mt)
#pragma unroll
            for (int nt = 0; nt < 4; ++nt) acc[mt][nt] = (f32x4){0.f, 0.f, 0.f, 0.f};

#pragma unroll 2
        for (int s = 0; s < 8; ++s) {
            short8 bfr[4];
#pragma unroll
            for (int nt = 0; nt < 4; ++nt) {
                int ntile = wc * 4 + nt;
                size_t off = ((size_t)((ntile * 8 + s) * 64 + lane)) * 8;
                bfr[nt] = *reinterpret_cast<const short8*>(Wfrag + off);
            }
            const int kus = s * 32 + lq * 8;
#pragma unroll
            for (int mt = 0; mt < 2; ++mt) {
                int r   = wr * 32 + mt * 16 + lr;
                int idx = r * 256 + (kus ^ ((r & 7) << 3));
                short8 a = *reinterpret_cast<const short8*>(&buf[idx]);
#pragma unroll
                for (int nt = 0; nt < 4; ++nt)
                    acc[mt][nt] = __builtin_amdgcn_mfma_f32_16x16x32_bf16(bfr[nt], a, acc[mt][nt], 0, 0, 0);
            }
        }

        // C-store for tile tt (global, no barrier needed)
        const int bm = bm0 + tt;
#pragma unroll
        for (int nt = 0; nt < 4; ++nt) {
            int n0 = wc * 64 + nt * 16 + lq * 4;
#pragma unroll
            for (int mt = 0; mt < 2; ++mt) {
                int row = bm * 64 + wr * 32 + mt * 16 + lr;
                ushort4 o;
                o.x = f2bf(acc[mt][nt][0] + bb[nt].x);
                o.y = f2bf(acc[mt][nt][1] + bb[nt].y);
                o.z = f2bf(acc[mt][nt][2] + bb[nt].z);
                o.w = f2bf(acc[mt][nt][3] + bb[nt].w);
                *reinterpret_cast<ushort4*>(&C[(size_t)row * 256 + n0]) = o;
            }
        }

        if (tt < 3) {
            stage_write((tt + 1) & 1);   // buf[(tt+1)&1] last read in iter tt-1,
            __syncthreads();             // separated by that iter's barrier
        }
    }
}

// ---------------------------------------------------------------------------
// Fused hs-projections via bf16 MFMA: hs = hidden+pos staged ONCE;
// off_raw[M][256] = hs @ W_off + b_off  (ntiles 0..15 of WfragQK)
// logits[M][128]  = hs @ W_attn + b_attn (ntiles 16..23, stored at +65536)
// M=7200 (113 blocks, row-guarded). 8 waves (2x4), 6 ntiles/wave, acc[2][6].
__global__ __launch_bounds__(512) void gemm_qk_mfma(const float* __restrict__ A1,
                                                    const float* __restrict__ A2,
                                                    const unsigned short* __restrict__ WfragQK,
                                                    const float* __restrict__ bo,
                                                    const float* __restrict__ ba,
                                                    float* __restrict__ off_raw,
                                                    float* __restrict__ logits, int M) {
    __shared__ unsigned short As[64 * 256];

    const int t  = threadIdx.x;
    const int bm = blockIdx.x;
    const int maxr = M - bm * 64;

    const float4* A14 = reinterpret_cast<const float4*>(A1 + (size_t)bm * 64 * 256);
    const float4* A24 = reinterpret_cast<const float4*>(A2 + (size_t)bm * 64 * 256);
#pragma unroll
    for (int i = 0; i < 4; ++i) {
        int c = i * 512 + t;
        int row = c >> 5;
        int kus = (c & 31) * 8;
        float4 v0 = make_float4(0.f,0.f,0.f,0.f), v1 = v0;
        if (row < maxr) {
            float4 x0 = A14[c * 2], y0 = A24[c * 2];
            float4 x1 = A14[c * 2 + 1], y1 = A24[c * 2 + 1];
            v0 = make_float4(x0.x + y0.x, x0.y + y0.y, x0.z + y0.z, x0.w + y0.w);
            v1 = make_float4(x1.x + y1.x, x1.y + y1.y, x1.z + y1.z, x1.w + y1.w);
        }
        union { short8 v; unsigned short u[8]; } pk;
        pk.u[0] = f2bf(v0.x); pk.u[1] = f2bf(v0.y); pk.u[2] = f2bf(v0.z); pk.u[3] = f2bf(v0.w);
        pk.u[4] = f2bf(v1.x); pk.u[5] = f2bf(v1.y); pk.u[6] = f2bf(v1.z); pk.u[7] = f2bf(v1.w);
        int idx = row * 256 + (kus ^ ((row & 7) << 3));
        *reinterpret_cast<short8*>(&As[idx]) = pk.v;
    }

    const int lane = t & 63;
    const int w    = t >> 6;
    const int wr   = w >> 2, wc = w & 3;
    const int lq   = lane >> 4, lr = lane & 15;

    f32x4 acc[2][6];
#pragma unroll
    for (int mt = 0; mt < 2; ++mt)
#pragma unroll
        for (int nt = 0; nt < 6; ++nt) acc[mt][nt] = (f32x4){0.f, 0.f, 0.f, 0.f};

    __syncthreads();

#pragma unroll 2
    for (int s = 0; s < 8; ++s) {
        short8 bfr[6];
#pragma unroll
        for (int nt = 0; nt < 6; ++nt) {
            int ntc = wc * 6 + nt;                // 0..23
            const unsigned short* p = (ntc < 16)
                ? WfragQK + ((size_t)(ntc * 8 + s)) * 512
                : WfragQK + 65536 + ((size_t)((ntc - 16) * 8 + s)) * 512;
            bfr[nt] = *reinterpret_cast<const short8*>(p + lane * 8);
        }
        const int kus = s * 32 + lq * 8;
#pragma unroll
        for (int mt = 0; mt < 2; ++mt) {
            int r   = wr * 32 + mt * 16 + lr;
            int idx = r * 256 + (kus ^ ((r & 7) << 3));
            short8 a = *reinterpret_cast<const short8*>(&As[idx]);
#pragma unroll
            for (int nt = 0; nt < 6; ++nt)
                acc[mt][nt] = __builtin_amdgcn_mfma_f32_16x16x32_bf16(bfr[nt], a, acc[mt][nt], 0, 0, 0);
        }
    }

    // Epilogue: f32 stores, 16B wide, row-guarded. D: col=hs-row(m), row=n.
#pragma unroll
    for (int nt = 0; nt < 6; ++nt) {
        int ntc = wc * 6 + nt;
        float* base; int stride, n0;
        float4 bb;
        if (ntc < 16) { n0 = ntc * 16 + lq * 4;        base = off_raw; stride = 256;
                        bb = *reinterpret_cast<const float4*>(&bo[n0]); }
        else          { n0 = (ntc - 16) * 16 + lq * 4; base = logits;  stride = 128;
                        bb = *reinterpret_cast<const float4*>(&ba[n0]); }
#pragma unroll
        for (int mt = 0; mt < 2; ++mt) {
            int r = wr * 32 + mt * 16 + lr;
            if (r < maxr) {
                int row = bm * 64 + r;
                float4 o = make_float4(acc[mt][nt][0] + bb.x, acc[mt][nt][1] + bb.y,
                                       acc[mt][nt][2] + bb.z, acc[mt][nt][3] + bb.w);
                *reinterpret_cast<float4*>(&base[(size_t)row * stride + n0]) = o;
            }
        }
    }
}

// ---------------------------------------------------------------------------
// out = out_pre @ W_out + b via bf16 MFMA, f32 output. M=7200, row-guarded.
__global__ __launch_bounds__(512) void gemm_out_mfma(const float* __restrict__ A,
                                                     const unsigned short* __restrict__ Wfrag,
                                                     const float* __restrict__ bias,
                                                     float* __restrict__ C, int M) {
    __shared__ unsigned short As[64 * 256];

    const int t  = threadIdx.x;
    const int bm = blockIdx.x;
    const int maxr = M - bm * 64;

    const float4* A4 = reinterpret_cast<const float4*>(A + (size_t)bm * 64 * 256);
#pragma unroll
    for (int i = 0; i < 4; ++i) {
        int c = i * 512 + t;
        int row = c >> 5;
        int kus = (c & 31) * 8;
        float4 v0 = make_float4(0.f,0.f,0.f,0.f), v1 = v0;
        if (row < maxr) { v0 = A4[c * 2]; v1 = A4[c * 2 + 1]; }
        union { short8 v; unsigned short u[8]; } pk;
        pk.u[0] = f2bf(v0.x); pk.u[1] = f2bf(v0.y); pk.u[2] = f2bf(v0.z); pk.u[3] = f2bf(v0.w);
        pk.u[4] = f2bf(v1.x); pk.u[5] = f2bf(v1.y); pk.u[6] = f2bf(v1.z); pk.u[7] = f2bf(v1.w);
        int idx = row * 256 + (kus ^ ((row & 7) << 3));
        *reinterpret_cast<short8*>(&As[idx]) = pk.v;
    }

    const int lane = t & 63;
    const int w    = t >> 6;
    const int wr   = w >> 2, wc = w & 3;
    const int lq   = lane >> 4, lr = lane & 15;

    f32x4 acc[2][4];
#pragma unroll
    for (int mt = 0; mt < 2; ++mt)
#pragma unroll
        for (int nt = 0; nt < 4; ++nt) acc[mt][nt] = (f32x4){0.f, 0.f, 0.f, 0.f};

    __syncthreads();

#pragma unroll 2
    for (int s = 0; s < 8; ++s) {
        short8 bfr[4];
#pragma unroll
        for (int nt = 0; nt < 4; ++nt) {
            int ntile = wc * 4 + nt;
            size_t off = ((size_t)((ntile * 8 + s) * 64 + lane)) * 8;
            bfr[nt] = *reinterpret_cast<const short8*>(Wfrag + off);
        }
        const int kus = s * 32 + lq * 8;
#pragma unroll
        for (int mt = 0; mt < 2; ++mt) {
            int r   = wr * 32 + mt * 16 + lr;
            int idx = r * 256 + (kus ^ ((r & 7) << 3));
            short8 a = *reinterpret_cast<const short8*>(&As[idx]);
#pragma unroll
            for (int nt = 0; nt < 4; ++nt)
                acc[mt][nt] = __builtin_amdgcn_mfma_f32_16x16x32_bf16(bfr[nt], a, acc[mt][nt], 0, 0, 0);
        }
    }

#pragma unroll
    for (int nt = 0; nt < 4; ++nt) {
        int n0 = wc * 64 + nt * 16 + lq * 4;
        float4 bb = *reinterpret_cast<const float4*>(&bias[n0]);
#pragma unroll
        for (int mt = 0; mt < 2; ++mt) {
            int r = wr * 32 + mt * 16 + lr;
            if (r < maxr) {
                int row = bm * 64 + r;
                float4 o = make_float4(acc[mt][nt][0] + bb.x, acc[mt][nt][1] + bb.y,
                                       acc[mt][nt][2] + bb.z, acc[mt][nt][3] + bb.w);
                *reinterpret_cast<float4*>(&C[(size_t)row * 256 + n0]) = o;
            }
        }
    }
}

// ---------------------------------------------------------------------------
// Softmax over groups of 16 logits: one thread per (b,q,h)
__global__ __launch_bounds__(256) void softmax_k(const float* __restrict__ logits,
                                                 float* __restrict__ attw) {
    int tid = blockIdx.x * 256 + threadIdx.x;  // < 57600
    const float4* in = reinterpret_cast<const float4*>(logits + (size_t)tid * 16);
    float v[16];
    float4 a0 = in[0], a1 = in[1], a2 = in[2], a3 = in[3];
    v[0]=a0.x; v[1]=a0.y; v[2]=a0.z; v[3]=a0.w;
    v[4]=a1.x; v[5]=a1.y; v[6]=a1.z; v[7]=a1.w;
    v[8]=a2.x; v[9]=a2.y; v[10]=a2.z; v[11]=a2.w;
    v[12]=a3.x; v[13]=a3.y; v[14]=a3.z; v[15]=a3.w;
    float m = v[0];
#pragma unroll
    for (int i = 1; i < 16; ++i) m = fmaxf(m, v[i]);
    float s = 0.f;
#pragma unroll
    for (int i = 0; i < 16; ++i) { v[i] = __expf(v[i] - m); s += v[i]; }
    float inv = 1.f / s;
    float4* o = reinterpret_cast<float4*>(attw + (size_t)tid * 16);
    o[0] = make_float4(v[0]*inv, v[1]*inv, v[2]*inv, v[3]*inv);
    o[1] = make_float4(v[4]*inv, v[5]*inv, v[6]*inv, v[7]*inv);
    o[2] = make_float4(v[8]*inv, v[9]*inv, v[10]*inv, v[11]*inv);
    o[3] = make_float4(v[12]*inv, v[13]*inv, v[14]*inv, v[15]*inv);
}

// ---------------------------------------------------------------------------
// Bilinear sampling + attention-weighted sum.
// 8 lanes per (b,q,h) group, each lane handles 4 channels (bf16x4 = 8B loads).
__global__ __launch_bounds__(256) void sample_k(const unsigned short* __restrict__ value,
                                                const float* __restrict__ off_raw,
                                                const float* __restrict__ refp,
                                                const float* __restrict__ attw,
                                                float* __restrict__ out_pre) {
    const int lane = threadIdx.x & 7;
    const int g    = threadIdx.x >> 3;
    const int idx  = blockIdx.x * 32 + g;      // < 57600
    const int h    = idx & 7;
    const int bq   = idx >> 3;
    const int b    = bq / Qn;

    const ushort4* v4 = reinterpret_cast<const ushort4*>(value);
    const size_t vbase4 = (size_t)b * (Sn * 64) + h * 8 + lane;

    const float* offs = off_raw + (size_t)bq * 256 + h * 32;
    const float* aw   = attw    + (size_t)bq * 128 + h * 16;
    const float* rp   = refp    + (size_t)bq * 8;

    float acc0 = 0.f, acc1 = 0.f, acc2 = 0.f, acc3 = 0.f;

#pragma unroll
    for (int lvl = 0; lvl < 4; ++lvl) {
        const int Wl = LVL_W[lvl], Hl = LVL_H[lvl];
        const float fW = (float)Wl, fH = (float)Hl;
        const float rx = rp[lvl * 2 + 0], ry = rp[lvl * 2 + 1];
        const size_t lb4 = vbase4 + (size_t)LVL_START[lvl] * 64;
#pragma unroll
        for (int p = 0; p < 4; ++p) {
            const float w  = aw[lvl * 4 + p];
            const float locx = rx + offs[lvl * 8 + p * 2 + 0] / fW;
            const float locy = ry + offs[lvl * 8 + p * 2 + 1] / fH;
            const float x = locx * fW - 0.5f;
            const float y = locy * fH - 0.5f;
            const float x0f = floorf(x), y0f = floorf(y);
            const int x0 = (int)x0f, y0 = (int)y0f;
            const int x1 = x0 + 1, y1 = y0 + 1;
            const float fx = x - x0f, fy = y - y0f;
            const float vx0 = (x0 >= 0 && x0 < Wl) ? 1.f : 0.f;
            const float vx1 = (x1 >= 0 && x1 < Wl) ? 1.f : 0.f;
            const float vy0 = (y0 >= 0 && y0 < Hl) ? 1.f : 0.f;
            const float vy1 = (y1 >= 0 && y1 < Hl) ? 1.f : 0.f;
            const int xc0 = min(max(x0, 0), Wl - 1);
            const int xc1 = min(max(x1, 0), Wl - 1);
            const int yc0 = min(max(y0, 0), Hl - 1);
            const int yc1 = min(max(y1, 0), Hl - 1);
            const float w00 = w * (1.f - fx) * (1.f - fy) * vx0 * vy0;
            const float w01 = w * fx         * (1.f - fy) * vx1 * vy0;
            const float w10 = w * (1.f - fx) * fy         * vx0 * vy1;
            const float w11 = w * fx         * fy         * vx1 * vy1;

            const ushort4 t00 = v4[lb4 + (size_t)(yc0 * Wl + xc0) * 64];
            const ushort4 t01 = v4[lb4 + (size_t)(yc0 * Wl + xc1) * 64];
            const ushort4 t10 = v4[lb4 + (size_t)(yc1 * Wl + xc0) * 64];
            const ushort4 t11 = v4[lb4 + (size_t)(yc1 * Wl + xc1) * 64];

            acc0 += w00 * bf2f(t00.x) + w01 * bf2f(t01.x) + w10 * bf2f(t10.x) + w11 * bf2f(t11.x);
            acc1 += w00 * bf2f(t00.y) + w01 * bf2f(t01.y) + w10 * bf2f(t10.y) + w11 * bf2f(t11.y);
            acc2 += w00 * bf2f(t00.z) + w01 * bf2f(t01.z) + w10 * bf2f(t10.z) + w11 * bf2f(t11.z);
            acc3 += w00 * bf2f(t00.w) + w01 * bf2f(t01.w) + w10 * bf2f(t10.w) + w11 * bf2f(t11.w);
        }
    }
    reinterpret_cast<float4*>(out_pre)[(size_t)bq * 64 + h * 8 + lane] =
        make_float4(acc0, acc1, acc2, acc3);
}

// ---------------------------------------------------------------------------
extern "C" void kernel_launch(void* const* d_in, const int* in_sizes, int n_in,
                              void* d_out, int out_size, void* d_ws, size_t ws_size,
                              hipStream_t stream) {
    const float* hidden = (const float*)d_in[0];
    const float* ehs    = (const float*)d_in[1];
    const float* pos    = (const float*)d_in[2];
    const float* refp   = (const float*)d_in[3];
    const float* Wv   = (const float*)d_in[5];
    const float* bv   = (const float*)d_in[6];
    const float* Wo   = (const float*)d_in[7];
    const float* bo   = (const float*)d_in[8];
    const float* Wa   = (const float*)d_in[9];
    const float* ba   = (const float*)d_in[10];
    const float* Wout = (const float*)d_in[11];
    const float* bout = (const float*)d_in[12];

    float* ws = (float*)d_ws;
    // Old hs slot (1.8M f32) reused for weight fragments:
    unsigned short* WfragQK = (unsigned short*)ws;             // 98,304 bf16 (off + attn at +65536)
    unsigned short* WfragO  = (unsigned short*)(ws + 49152);   // 65,536 bf16
    float* off_raw = ws + 1843200;       // 1,843,200 f32
    float* logits  = ws + 3686400;       //   921,600 f32
    float* out_pre = ws + 4608000;       // 1,843,200 f32
    unsigned short* value = (unsigned short*)(ws + 6451200);  // 44,564,480 bf16
    // WfragV aliases out_pre's region: lifetime [wfrag_k, gemm_value_mfma],
    // out_pre lifetime [sample_k, gemm_out_mfma] — disjoint on the stream.
    unsigned short* WfragV = (unsigned short*)out_pre;         // 65,536 bf16

    float* outv = (float*)d_out;         // (B,Q,D) f32
    float* attw = outv + 1843200;        // (B,Q,NH,NL,NP) f32

    wfrag_k<<<32, 256, 0, stream>>>(Wv,   256, WfragV);
    wfrag_k<<<32, 256, 0, stream>>>(Wout, 256, WfragO);
    wfrag_k<<<32, 256, 0, stream>>>(Wo,   256, WfragQK);
    wfrag_k<<<16, 256, 0, stream>>>(Wa,   128, WfragQK + 65536);
    gemm_value_mfma<<<680, 512, 0, stream>>>(ehs, WfragV, bv, value);
    gemm_qk_mfma<<<113, 512, 0, stream>>>(hidden, pos, WfragQK, bo, ba, off_raw, logits, Bc * Qn);
    softmax_k<<<225, 256, 0, stream>>>(logits, attw);
    sample_k<<<1800, 256, 0, stream>>>(value, off_raw, refp, attw, out_pre);
    gemm_out_mfma<<<113, 512, 0, stream>>>(out_pre, WfragO, bout, outv, Bc * Qn);
}

// Round 14
// 147.530 us; speedup vs baseline: 1.0319x; 1.0319x over previous
//
#include <hip/hip_runtime.h>
#include <hip/hip_bf16.h>

// Problem constants (fixed by setup_inputs)
constexpr int Bc  = 8;
constexpr int Qn  = 900;
constexpr int Sn  = 21760;

__constant__ int LVL_START[4] = {0, 16384, 20480, 21504};

typedef __attribute__((ext_vector_type(8))) short short8;
typedef __attribute__((ext_vector_type(4))) float f32x4;

__device__ __forceinline__ unsigned short f2bf(float x) {
    union { float f; unsigned int u; } z; z.f = x;
    unsigned int r = (z.u + 0x7FFF + ((z.u >> 16) & 1)) >> 16;   // RTN-even
    return (unsigned short)r;
}
__device__ __forceinline__ float bf2f(unsigned short u) {
    union { unsigned int i; float f; } z;
    z.i = ((unsigned int)u) << 16;
    return z.f;
}

// ---------------------------------------------------------------------------
// Pre-pass: pack a [K=256][N] f32 row-major weight into bf16 MFMA fragment
// order. frag_id = ntile*8 + kstep; lane l supplies
// W[k = kstep*32 + (l>>4)*8 + j][n = ntile*16 + (l&15)], j=0..7.
__global__ __launch_bounds__(256) void wfrag_k(const float* __restrict__ W, int N,
                                               unsigned short* __restrict__ out) {
    int gid = blockIdx.x * 256 + threadIdx.x;
    int frag = gid >> 6, lane = gid & 63;
    int ntile = frag >> 3, s = frag & 7;
    int n = ntile * 16 + (lane & 15);
    int kb = s * 32 + (lane >> 4) * 8;
    unsigned short* o = out + (size_t)gid * 8;
#pragma unroll
    for (int j = 0; j < 8; ++j)
        o[j] = f2bf(W[(size_t)(kb + j) * N + n]);
}

// ---------------------------------------------------------------------------
// UBER GEMM: one dispatch, two block roles.
//   blocks 0..2719   : value = ehs @ W_value + b  (bf16 out)  [r12 body, 105us]
//   blocks 2720..2832: {off_raw, logits} = (hidden+pos) @ {W_off, W_attn}
// The value role runs with every pipe <25% busy (latency-pinned across
// r6-r13); the 113 qk blocks fill its holes nearly free.
__global__ __launch_bounds__(512) void uber_gemm(
        const float* __restrict__ Aehs, const unsigned short* __restrict__ WfragV,
        const float* __restrict__ bv, unsigned short* __restrict__ Cval,
        const float* __restrict__ A1, const float* __restrict__ A2,
        const unsigned short* __restrict__ WfragQK,
        const float* __restrict__ bo, const float* __restrict__ ba,
        float* __restrict__ off_raw, float* __restrict__ logits, int Mqk) {
    __shared__ unsigned short As[64 * 256];   // 32 KB bf16, XOR-swizzled rows

    const int t    = threadIdx.x;
    const int lane = t & 63;
    const int w    = t >> 6;                  // 0..7
    const int wr   = w >> 2, wc = w & 3;      // wave grid 2x4
    const int lq   = lane >> 4, lr = lane & 15;

    if (blockIdx.x < 2720) {
        // ================= VALUE role =================
        const int bm = blockIdx.x;
        const float4* A4 = reinterpret_cast<const float4*>(Aehs + (size_t)bm * 64 * 256);
#pragma unroll
        for (int i = 0; i < 4; ++i) {
            int c = i * 512 + t;
            int row = c >> 5;
            int kus = (c & 31) * 8;
            float4 v0 = A4[c * 2], v1 = A4[c * 2 + 1];
            union { short8 v; unsigned short u[8]; } pk;
            pk.u[0] = f2bf(v0.x); pk.u[1] = f2bf(v0.y); pk.u[2] = f2bf(v0.z); pk.u[3] = f2bf(v0.w);
            pk.u[4] = f2bf(v1.x); pk.u[5] = f2bf(v1.y); pk.u[6] = f2bf(v1.z); pk.u[7] = f2bf(v1.w);
            int idx = row * 256 + (kus ^ ((row & 7) << 3));
            *reinterpret_cast<short8*>(&As[idx]) = pk.v;
        }

        f32x4 acc[2][4];
#pragma unroll
        for (int mt = 0; mt < 2; ++mt)
#pragma unroll
            for (int nt = 0; nt < 4; ++nt) acc[mt][nt] = (f32x4){0.f, 0.f, 0.f, 0.f};

        __syncthreads();

#pragma unroll 2
        for (int s = 0; s < 8; ++s) {
            short8 bfr[4];
#pragma unroll
            for (int nt = 0; nt < 4; ++nt) {
                int ntile = wc * 4 + nt;
                size_t off = ((size_t)((ntile * 8 + s) * 64 + lane)) * 8;
                bfr[nt] = *reinterpret_cast<const short8*>(WfragV + off);
            }
            const int kus = s * 32 + lq * 8;
#pragma unroll
            for (int mt = 0; mt < 2; ++mt) {
                int r   = wr * 32 + mt * 16 + lr;
                int idx = r * 256 + (kus ^ ((r & 7) << 3));
                short8 a = *reinterpret_cast<const short8*>(&As[idx]);
#pragma unroll
                for (int nt = 0; nt < 4; ++nt)
                    acc[mt][nt] = __builtin_amdgcn_mfma_f32_16x16x32_bf16(bfr[nt], a, acc[mt][nt], 0, 0, 0);
            }
        }

#pragma unroll
        for (int nt = 0; nt < 4; ++nt) {
            int n0 = wc * 64 + nt * 16 + lq * 4;
            float4 bb = *reinterpret_cast<const float4*>(&bv[n0]);
#pragma unroll
            for (int mt = 0; mt < 2; ++mt) {
                int row = bm * 64 + wr * 32 + mt * 16 + lr;
                ushort4 o;
                o.x = f2bf(acc[mt][nt][0] + bb.x);
                o.y = f2bf(acc[mt][nt][1] + bb.y);
                o.z = f2bf(acc[mt][nt][2] + bb.z);
                o.w = f2bf(acc[mt][nt][3] + bb.w);
                *reinterpret_cast<ushort4*>(&Cval[(size_t)row * 256 + n0]) = o;
            }
        }
    } else {
        // ================= QK role =================
        const int bm = blockIdx.x - 2720;
        const int maxr = Mqk - bm * 64;

        const float4* A14 = reinterpret_cast<const float4*>(A1 + (size_t)bm * 64 * 256);
        const float4* A24 = reinterpret_cast<const float4*>(A2 + (size_t)bm * 64 * 256);
#pragma unroll
        for (int i = 0; i < 4; ++i) {
            int c = i * 512 + t;
            int row = c >> 5;
            int kus = (c & 31) * 8;
            float4 v0 = make_float4(0.f,0.f,0.f,0.f), v1 = v0;
            if (row < maxr) {
                float4 x0 = A14[c * 2], y0 = A24[c * 2];
                float4 x1 = A14[c * 2 + 1], y1 = A24[c * 2 + 1];
                v0 = make_float4(x0.x + y0.x, x0.y + y0.y, x0.z + y0.z, x0.w + y0.w);
                v1 = make_float4(x1.x + y1.x, x1.y + y1.y, x1.z + y1.z, x1.w + y1.w);
            }
            union { short8 v; unsigned short u[8]; } pk;
            pk.u[0] = f2bf(v0.x); pk.u[1] = f2bf(v0.y); pk.u[2] = f2bf(v0.z); pk.u[3] = f2bf(v0.w);
            pk.u[4] = f2bf(v1.x); pk.u[5] = f2bf(v1.y); pk.u[6] = f2bf(v1.z); pk.u[7] = f2bf(v1.w);
            int idx = row * 256 + (kus ^ ((row & 7) << 3));
            *reinterpret_cast<short8*>(&As[idx]) = pk.v;
        }

        f32x4 acc[2][6];
#pragma unroll
        for (int mt = 0; mt < 2; ++mt)
#pragma unroll
            for (int nt = 0; nt < 6; ++nt) acc[mt][nt] = (f32x4){0.f, 0.f, 0.f, 0.f};

        __syncthreads();

#pragma unroll 2
        for (int s = 0; s < 8; ++s) {
            short8 bfr[6];
#pragma unroll
            for (int nt = 0; nt < 6; ++nt) {
                int ntc = wc * 6 + nt;                // 0..23
                const unsigned short* p = (ntc < 16)
                    ? WfragQK + ((size_t)(ntc * 8 + s)) * 512
                    : WfragQK + 65536 + ((size_t)((ntc - 16) * 8 + s)) * 512;
                bfr[nt] = *reinterpret_cast<const short8*>(p + lane * 8);
            }
            const int kus = s * 32 + lq * 8;
#pragma unroll
            for (int mt = 0; mt < 2; ++mt) {
                int r   = wr * 32 + mt * 16 + lr;
                int idx = r * 256 + (kus ^ ((r & 7) << 3));
                short8 a = *reinterpret_cast<const short8*>(&As[idx]);
#pragma unroll
                for (int nt = 0; nt < 6; ++nt)
                    acc[mt][nt] = __builtin_amdgcn_mfma_f32_16x16x32_bf16(bfr[nt], a, acc[mt][nt], 0, 0, 0);
            }
        }

#pragma unroll
        for (int nt = 0; nt < 6; ++nt) {
            int ntc = wc * 6 + nt;
            float* base; int stride, n0;
            float4 bb;
            if (ntc < 16) { n0 = ntc * 16 + lq * 4;        base = off_raw; stride = 256;
                            bb = *reinterpret_cast<const float4*>(&bo[n0]); }
            else          { n0 = (ntc - 16) * 16 + lq * 4; base = logits;  stride = 128;
                            bb = *reinterpret_cast<const float4*>(&ba[n0]); }
#pragma unroll
            for (int mt = 0; mt < 2; ++mt) {
                int r = wr * 32 + mt * 16 + lr;
                if (r < maxr) {
                    int row = bm * 64 + r;
                    float4 o = make_float4(acc[mt][nt][0] + bb.x, acc[mt][nt][1] + bb.y,
                                           acc[mt][nt][2] + bb.z, acc[mt][nt][3] + bb.w);
                    *reinterpret_cast<float4*>(&base[(size_t)row * stride + n0]) = o;
                }
            }
        }
    }
}

// ---------------------------------------------------------------------------
// out = out_pre @ W_out + b via bf16 MFMA, f32 output. M=7200, row-guarded.
__global__ __launch_bounds__(512) void gemm_out_mfma(const float* __restrict__ A,
                                                     const unsigned short* __restrict__ Wfrag,
                                                     const float* __restrict__ bias,
                                                     float* __restrict__ C, int M) {
    __shared__ unsigned short As[64 * 256];

    const int t  = threadIdx.x;
    const int bm = blockIdx.x;
    const int maxr = M - bm * 64;

    const float4* A4 = reinterpret_cast<const float4*>(A + (size_t)bm * 64 * 256);
#pragma unroll
    for (int i = 0; i < 4; ++i) {
        int c = i * 512 + t;
        int row = c >> 5;
        int kus = (c & 31) * 8;
        float4 v0 = make_float4(0.f,0.f,0.f,0.f), v1 = v0;
        if (row < maxr) { v0 = A4[c * 2]; v1 = A4[c * 2 + 1]; }
        union { short8 v; unsigned short u[8]; } pk;
        pk.u[0] = f2bf(v0.x); pk.u[1] = f2bf(v0.y); pk.u[2] = f2bf(v0.z); pk.u[3] = f2bf(v0.w);
        pk.u[4] = f2bf(v1.x); pk.u[5] = f2bf(v1.y); pk.u[6] = f2bf(v1.z); pk.u[7] = f2bf(v1.w);
        int idx = row * 256 + (kus ^ ((row & 7) << 3));
        *reinterpret_cast<short8*>(&As[idx]) = pk.v;
    }

    const int lane = t & 63;
    const int w    = t >> 6;
    const int wr   = w >> 2, wc = w & 3;
    const int lq   = lane >> 4, lr = lane & 15;

    f32x4 acc[2][4];
#pragma unroll
    for (int mt = 0; mt < 2; ++mt)
#pragma unroll
        for (int nt = 0; nt < 4; ++nt) acc[mt][nt] = (f32x4){0.f, 0.f, 0.f, 0.f};

    __syncthreads();

#pragma unroll 2
    for (int s = 0; s < 8; ++s) {
        short8 bfr[4];
#pragma unroll
        for (int nt = 0; nt < 4; ++nt) {
            int ntile = wc * 4 + nt;
            size_t off = ((size_t)((ntile * 8 + s) * 64 + lane)) * 8;
            bfr[nt] = *reinterpret_cast<const short8*>(Wfrag + off);
        }
        const int kus = s * 32 + lq * 8;
#pragma unroll
        for (int mt = 0; mt < 2; ++mt) {
            int r   = wr * 32 + mt * 16 + lr;
            int idx = r * 256 + (kus ^ ((r & 7) << 3));
            short8 a = *reinterpret_cast<const short8*>(&As[idx]);
#pragma unroll
            for (int nt = 0; nt < 4; ++nt)
                acc[mt][nt] = __builtin_amdgcn_mfma_f32_16x16x32_bf16(bfr[nt], a, acc[mt][nt], 0, 0, 0);
        }
    }

#pragma unroll
    for (int nt = 0; nt < 4; ++nt) {
        int n0 = wc * 64 + nt * 16 + lq * 4;
        float4 bb = *reinterpret_cast<const float4*>(&bias[n0]);
#pragma unroll
        for (int mt = 0; mt < 2; ++mt) {
            int r = wr * 32 + mt * 16 + lr;
            if (r < maxr) {
                int row = bm * 64 + r;
                float4 o = make_float4(acc[mt][nt][0] + bb.x, acc[mt][nt][1] + bb.y,
                                       acc[mt][nt][2] + bb.z, acc[mt][nt][3] + bb.w);
                *reinterpret_cast<float4*>(&C[(size_t)row * 256 + n0]) = o;
            }
        }
    }
}

// ---------------------------------------------------------------------------
// Fused softmax + bilinear sampling. 16 lanes per (b,q,h) group:
//   ch = L&7  -> 4-channel group (as before)
//   pq = L>>3 -> point half (levels 0-1 vs levels 2-3; 8 points each)
// Per-thread serial gather chain: 32 loads (was 64); 2x the threads (TLP for
// a latency-bound gather). Softmax computed inline (redundant per lane);
// lanes pq==0 && ch<4 write the attw output; cross-half reduce via shfl_xor(8)
// (groups are 16-aligned in tid, so the partner stays in-group).
__global__ __launch_bounds__(256) void sample_fused_k(const unsigned short* __restrict__ value,
                                                      const float* __restrict__ off_raw,
                                                      const float* __restrict__ refp,
                                                      const float* __restrict__ logits,
                                                      float* __restrict__ attw,
                                                      float* __restrict__ out_pre) {
    const int L    = threadIdx.x & 15;
    const int g    = threadIdx.x >> 4;         // 0..15
    const int idx  = blockIdx.x * 16 + g;      // (b*Q+q)*8 + h, < 57600
    const int h    = idx & 7;
    const int bq   = idx >> 3;
    const int b    = bq / Qn;
    const int ch   = L & 7;
    const int pq   = L >> 3;

    // ---- inline softmax over this group's 16 logits ----
    const float4* lg = reinterpret_cast<const float4*>(logits + (size_t)idx * 16);
    float v[16];
    float4 a0 = lg[0], a1 = lg[1], a2 = lg[2], a3 = lg[3];
    v[0]=a0.x; v[1]=a0.y; v[2]=a0.z; v[3]=a0.w;
    v[4]=a1.x; v[5]=a1.y; v[6]=a1.z; v[7]=a1.w;
    v[8]=a2.x; v[9]=a2.y; v[10]=a2.z; v[11]=a2.w;
    v[12]=a3.x; v[13]=a3.y; v[14]=a3.z; v[15]=a3.w;
    float m = v[0];
#pragma unroll
    for (int i = 1; i < 16; ++i) m = fmaxf(m, v[i]);
    float s = 0.f;
#pragma unroll
    for (int i = 0; i < 16; ++i) { v[i] = __expf(v[i] - m); s += v[i]; }
    float inv = 1.f / s;
#pragma unroll
    for (int i = 0; i < 16; ++i) v[i] *= inv;

    // attw output (B,Q,NH,16): lanes pq==0, ch<4 each write one float4
    if (pq == 0 && ch < 4) {
        float4 o;
        if      (ch == 0) o = make_float4(v[0],  v[1],  v[2],  v[3]);
        else if (ch == 1) o = make_float4(v[4],  v[5],  v[6],  v[7]);
        else if (ch == 2) o = make_float4(v[8],  v[9],  v[10], v[11]);
        else              o = make_float4(v[12], v[13], v[14], v[15]);
        reinterpret_cast<float4*>(attw + (size_t)idx * 16)[ch] = o;
    }

    // this half's 8 weights, statically selected (no runtime reg-array index)
    float w8[8];
#pragma unroll
    for (int i = 0; i < 8; ++i) w8[i] = (pq == 0) ? v[i] : v[i + 8];

    const ushort4* v4 = reinterpret_cast<const ushort4*>(value);
    const size_t vbase4 = (size_t)b * (Sn * 64) + h * 8 + ch;
    const float* offs = off_raw + (size_t)bq * 256 + h * 32;
    const float* rp   = refp    + (size_t)bq * 8;

    float acc0 = 0.f, acc1 = 0.f, acc2 = 0.f, acc3 = 0.f;

#pragma unroll
    for (int li = 0; li < 2; ++li) {
        const int lvl = pq * 2 + li;
        const int Wl = 128 >> lvl, Hl = 128 >> lvl;
        const float fW = (float)Wl, fH = (float)Hl;
        const float rx = rp[lvl * 2 + 0], ry = rp[lvl * 2 + 1];
        const size_t lb4 = vbase4 + (size_t)LVL_START[lvl] * 64;
#pragma unroll
        for (int p = 0; p < 4; ++p) {
            const float w  = w8[li * 4 + p];
            const float locx = rx + offs[lvl * 8 + p * 2 + 0] / fW;
            const float locy = ry + offs[lvl * 8 + p * 2 + 1] / fH;
            const float x = locx * fW - 0.5f;
            const float y = locy * fH - 0.5f;
            const float x0f = floorf(x), y0f = floorf(y);
            const int x0 = (int)x0f, y0 = (int)y0f;
            const int x1 = x0 + 1, y1 = y0 + 1;
            const float fx = x - x0f, fy = y - y0f;
            const float vx0 = (x0 >= 0 && x0 < Wl) ? 1.f : 0.f;
            const float vx1 = (x1 >= 0 && x1 < Wl) ? 1.f : 0.f;
            const float vy0 = (y0 >= 0 && y0 < Hl) ? 1.f : 0.f;
            const float vy1 = (y1 >= 0 && y1 < Hl) ? 1.f : 0.f;
            const int xc0 = min(max(x0, 0), Wl - 1);
            const int xc1 = min(max(x1, 0), Wl - 1);
            const int yc0 = min(max(y0, 0), Hl - 1);
            const int yc1 = min(max(y1, 0), Hl - 1);
            const float w00 = w * (1.f - fx) * (1.f - fy) * vx0 * vy0;
            const float w01 = w * fx         * (1.f - fy) * vx1 * vy0;
            const float w10 = w * (1.f - fx) * fy         * vx0 * vy1;
            const float w11 = w * fx         * fy         * vx1 * vy1;

            const ushort4 t00 = v4[lb4 + (size_t)(yc0 * Wl + xc0) * 64];
            const ushort4 t01 = v4[lb4 + (size_t)(yc0 * Wl + xc1) * 64];
            const ushort4 t10 = v4[lb4 + (size_t)(yc1 * Wl + xc0) * 64];
            const ushort4 t11 = v4[lb4 + (size_t)(yc1 * Wl + xc1) * 64];

            acc0 += w00 * bf2f(t00.x) + w01 * bf2f(t01.x) + w10 * bf2f(t10.x) + w11 * bf2f(t11.x);
            acc1 += w00 * bf2f(t00.y) + w01 * bf2f(t01.y) + w10 * bf2f(t10.y) + w11 * bf2f(t11.y);
            acc2 += w00 * bf2f(t00.z) + w01 * bf2f(t01.z) + w10 * bf2f(t10.z) + w11 * bf2f(t11.z);
            acc3 += w00 * bf2f(t00.w) + w01 * bf2f(t01.w) + w10 * bf2f(t10.w) + w11 * bf2f(t11.w);
        }
    }

    // reduce the two point-halves (partner = lane^8, within the 16-lane group)
    acc0 += __shfl_xor(acc0, 8);
    acc1 += __shfl_xor(acc1, 8);
    acc2 += __shfl_xor(acc2, 8);
    acc3 += __shfl_xor(acc3, 8);

    if (pq == 0)
        reinterpret_cast<float4*>(out_pre)[(size_t)bq * 64 + h * 8 + ch] =
            make_float4(acc0, acc1, acc2, acc3);
}

// ---------------------------------------------------------------------------
extern "C" void kernel_launch(void* const* d_in, const int* in_sizes, int n_in,
                              void* d_out, int out_size, void* d_ws, size_t ws_size,
                              hipStream_t stream) {
    const float* hidden = (const float*)d_in[0];
    const float* ehs    = (const float*)d_in[1];
    const float* pos    = (const float*)d_in[2];
    const float* refp   = (const float*)d_in[3];
    const float* Wv   = (const float*)d_in[5];
    const float* bv   = (const float*)d_in[6];
    const float* Wo   = (const float*)d_in[7];
    const float* bo   = (const float*)d_in[8];
    const float* Wa   = (const float*)d_in[9];
    const float* ba   = (const float*)d_in[10];
    const float* Wout = (const float*)d_in[11];
    const float* bout = (const float*)d_in[12];

    float* ws = (float*)d_ws;
    unsigned short* WfragQK = (unsigned short*)ws;             // 98,304 bf16 (off + attn at +65536)
    unsigned short* WfragO  = (unsigned short*)(ws + 49152);   // 65,536 bf16
    float* off_raw = ws + 1843200;       // 1,843,200 f32
    float* logits  = ws + 3686400;       //   921,600 f32
    float* out_pre = ws + 4608000;       // 1,843,200 f32
    unsigned short* value = (unsigned short*)(ws + 6451200);  // 44,564,480 bf16
    // WfragV aliases out_pre's region: lifetime [wfrag_k, uber_gemm],
    // out_pre lifetime [sample_fused_k, gemm_out_mfma] — disjoint on the stream.
    unsigned short* WfragV = (unsigned short*)out_pre;         // 65,536 bf16

    float* outv = (float*)d_out;         // (B,Q,D) f32
    float* attw = outv + 1843200;        // (B,Q,NH,NL,NP) f32

    wfrag_k<<<32, 256, 0, stream>>>(Wv,   256, WfragV);
    wfrag_k<<<32, 256, 0, stream>>>(Wout, 256, WfragO);
    wfrag_k<<<32, 256, 0, stream>>>(Wo,   256, WfragQK);
    wfrag_k<<<16, 256, 0, stream>>>(Wa,   128, WfragQK + 65536);
    uber_gemm<<<2833, 512, 0, stream>>>(ehs, WfragV, bv, value,
                                        hidden, pos, WfragQK, bo, ba,
                                        off_raw, logits, Bc * Qn);
    sample_fused_k<<<3600, 256, 0, stream>>>(value, off_raw, refp, logits, attw, out_pre);
    gemm_out_mfma<<<113, 512, 0, stream>>>(out_pre, WfragO, bout, outv, Bc * Qn);
}